// Round 10
// baseline (1550.514 us; speedup 1.0000x reference)
//
#include <hip/hip_runtime.h>
#include <hip/hip_bf16.h>

// AudioLSTM fused persistent kernel, v10: MFMA batch-tile recurrence.
// B=512, T=1000, IN=26, H1=64 (256 gate rows), H2=32 (128), FC 32->16->10.
// 64 blocks x 512 threads (8 waves). Each block owns E=8 batch elems (cols 0..7
// of a 16-wide MFMA tile; cols 8..15 compute garbage, never stored).
// Per step: gates = W * Z via mfma_f32_16x16x32_f16, Z = [x(32)|h1(64)|h2(32)]
// per elem in LDS (double-buffered by step parity, row stride 136 f16 = 272B).
//  w0..w3: LSTM1. Wave w owns gate-tiles {w, w+4, w+8, w+12} so i,f,g,o of a
//          unit land in the SAME lane across the 4 accumulators -> lane-local
//          cell update (units 16w + q*4 + reg). K-tiles: x, h1[0:32], h1[32:64].
//  w4..w5: LSTM2, one step behind (h2[s-1] from h1[s-1], h2[s-2]): tiles
//          {m2, m2+2, m2+4, m2+6}, units 16*m2 + q*4 + reg.
//  w6:     x[s+1] staging (f32/bf16 global -> f16 LDS).  w7: idle (FC at end).
// ONE barrier per step. All writes go to buf[s&1], all reads from buf[1-(s&1)].
// Layouts (guide §3, m89/m120): A[m=lane&15][k=(lane>>4)*8+j];
// B[k=(lane>>4)*8+j][n=lane&15]; D[m=(lane>>4)*4+reg][n=lane&15].

typedef __hip_bfloat16 bf16;
typedef _Float16 half8 __attribute__((ext_vector_type(8)));
typedef _Float16 half4 __attribute__((ext_vector_type(4)));
typedef float f32x4 __attribute__((ext_vector_type(4)));

#define T_STEPS 1000
#define IN_DIM  26
#define ZROW    136              // f16 per elem row: 32 x | 64 h1 | 32 h2 | 8 pad
#define ZSZ     (16 * ZROW)

__device__ __forceinline__ float bits2f(unsigned short h) {
    unsigned int u = ((unsigned int)h) << 16;
    return __uint_as_float(u);
}

__device__ __forceinline__ float ldv(const void* p, int idx, bool isb) {
    return isb ? bits2f(((const unsigned short*)p)[idx])
               : ((const float*)p)[idx];
}

__device__ __forceinline__ float sigm(float x) {
    return 1.0f / (1.0f + __expf(-x));
}

__device__ __forceinline__ float tanh_(float x) {
    float a = fabsf(x);
    float e = __expf(2.0f * a);
    float r = 1.0f - 2.0f / (e + 1.0f);
    return copysignf(r, x);
}

__device__ __forceinline__ f32x4 MFMA(half8 a, half8 b, f32x4 c) {
    return __builtin_amdgcn_mfma_f32_16x16x32_f16(a, b, c, 0, 0, 0);
}

__global__
__attribute__((amdgpu_flat_work_group_size(512, 512), amdgpu_waves_per_eu(2, 2)))
void lstm_mfma(const void* __restrict__ x,
               const void* __restrict__ w_ih1, const void* __restrict__ w_hh1,
               const void* __restrict__ b_ih1, const void* __restrict__ b_hh1,
               const void* __restrict__ w_ih2, const void* __restrict__ w_hh2,
               const void* __restrict__ b_ih2, const void* __restrict__ b_hh2,
               const void* __restrict__ w_fc1, const void* __restrict__ b_fc1,
               const void* __restrict__ w_fc2, const void* __restrict__ b_fc2,
               void* __restrict__ out)
{
    const int j    = threadIdx.x;       // 0..511
    const int wid  = j >> 6;            // wave 0..7
    const int lane = j & 63;
    const int el   = lane & 15;         // MFMA col: elem (valid < 8)
    const int q    = lane >> 4;         // MFMA quad
    const int e0   = blockIdx.x * 8;    // first elem of this block
    const long xstr = (long)(IN_DIM * T_STEPS);

    __shared__ __align__(16) _Float16 z[2][ZSZ];
    __shared__ float f1s[8][16];

    // ---- runtime dtype detection (uniform): w_ih1 ~ U(-1/8,1/8) ----
    bool isb = true;
    {
        const unsigned short* wu = (const unsigned short*)w_ih1;
        for (int k = 0; k < 64; ++k) {
            float v = fabsf(bits2f(wu[k]));
            if (!(v <= 0.1251f)) isb = false;
        }
    }

    // ---- per-role resident weights (A-frags) and biases ----
    half8 A[4][3];                      // [gate tg][K-tile]
    float bv[4][4];                     // bias per [gate tg][reg]
    if (wid < 4) {
        // LSTM1: tile (wid + 4*tg) -> rows tg*64 + 16*wid + m
#pragma unroll
        for (int tg = 0; tg < 4; ++tg) {
            const int row = tg * 64 + 16 * wid + el;
#pragma unroll
            for (int kt = 0; kt < 3; ++kt) {
                half8 a;
#pragma unroll
                for (int jj = 0; jj < 8; ++jj) {
                    const int k = kt * 32 + q * 8 + jj;
                    float v;
                    if (k < IN_DIM)      v = ldv(w_ih1, row * 26 + k, isb);
                    else if (k < 32)     v = 0.0f;
                    else                 v = ldv(w_hh1, row * 64 + (k - 32), isb);
                    a[jj] = (_Float16)v;
                }
                A[tg][kt] = a;
            }
#pragma unroll
            for (int r = 0; r < 4; ++r) {
                const int rb = tg * 64 + 16 * wid + q * 4 + r;
                bv[tg][r] = ldv(b_ih1, rb, isb) + ldv(b_hh1, rb, isb);
            }
        }
    } else if (wid < 6) {
        // LSTM2: tile (m2 + 2*tg) -> rows tg*32 + 16*m2 + m
        const int m2 = wid - 4;
#pragma unroll
        for (int tg = 0; tg < 4; ++tg) {
            const int row = tg * 32 + 16 * m2 + el;
#pragma unroll
            for (int kt = 0; kt < 3; ++kt) {
                half8 a;
#pragma unroll
                for (int jj = 0; jj < 8; ++jj) {
                    const int k = kt * 32 + q * 8 + jj;
                    float v;
                    if (k < 64) v = ldv(w_ih2, row * 64 + k, isb);
                    else        v = ldv(w_hh2, row * 32 + (k - 64), isb);
                    a[jj] = (_Float16)v;
                }
                A[tg][kt] = a;
            }
#pragma unroll
            for (int r = 0; r < 4; ++r) {
                const int rb = tg * 32 + 16 * m2 + q * 4 + r;
                bv[tg][r] = ldv(b_ih2, rb, isb) + ldv(b_hh2, rb, isb);
            }
        }
    }

    // ---- zero both state buffers, then stage x[0] into buf[1] ----
    {
        unsigned int* zi = (unsigned int*)z;
        for (int i = j; i < ZSZ; i += 512) zi[i] = 0u;   // 2*ZSZ f16 = ZSZ u32
    }
    __syncthreads();
    if (j < 256) {
        const int e = j >> 5, f = j & 31;
        if (f < IN_DIM)
            z[1][e * ZROW + f] =
                (_Float16)ldv(x, (long)(e0 + e) * xstr + f * T_STEPS + 0, isb);
    }
    __syncthreads();

    float c[4] = {0.f, 0.f, 0.f, 0.f};   // cell state (4 units/lane)

    for (int s = 0; s <= T_STEPS; ++s) {
        const int p = s & 1;
        const _Float16* zr = z[1 - p];
        _Float16* zw = z[p];

        if (wid < 4) {
            // ---------------- LSTM1 step s ----------------
            if (s < T_STEPS) {
                half8 bx = *(const half8*)(zr + el * ZROW +       q * 8);
                half8 b0 = *(const half8*)(zr + el * ZROW + 32 +  q * 8);
                half8 b1 = *(const half8*)(zr + el * ZROW + 64 +  q * 8);
                f32x4 zzero = {0.f, 0.f, 0.f, 0.f};
                f32x4 ai = zzero, af = zzero, ag = zzero, ao = zzero;
                ai = MFMA(A[0][0], bx, ai); af = MFMA(A[1][0], bx, af);
                ag = MFMA(A[2][0], bx, ag); ao = MFMA(A[3][0], bx, ao);
                ai = MFMA(A[0][1], b0, ai); af = MFMA(A[1][1], b0, af);
                ag = MFMA(A[2][1], b0, ag); ao = MFMA(A[3][1], b0, ao);
                ai = MFMA(A[0][2], b1, ai); af = MFMA(A[1][2], b1, af);
                ag = MFMA(A[2][2], b1, ag); ao = MFMA(A[3][2], b1, ao);
                half4 hv;
#pragma unroll
                for (int r = 0; r < 4; ++r) {
                    float gi = sigm(ai[r] + bv[0][r]);
                    float gf = sigm(af[r] + bv[1][r]);
                    float gg = tanh_(ag[r] + bv[2][r]);
                    float go = sigm(ao[r] + bv[3][r]);
                    c[r] = fmaf(gf, c[r], gi * gg);
                    hv[r] = (_Float16)(go * tanh_(c[r]));
                }
                // units 16*wid + 4*q + r -> h1 slots 32 + unit (contiguous 4)
                *(half4*)(zw + el * ZROW + 32 + 16 * wid + 4 * q) = hv;
            }
        } else if (wid < 6) {
            // ---------------- LSTM2 step s-1 ----------------
            if (s >= 1) {
                const int m2 = wid - 4;
                half8 b0 = *(const half8*)(zr + el * ZROW + 32 + q * 8);
                half8 b1 = *(const half8*)(zr + el * ZROW + 64 + q * 8);
                half8 b2 = *(const half8*)(zr + el * ZROW + 96 + q * 8);
                f32x4 zzero = {0.f, 0.f, 0.f, 0.f};
                f32x4 ai = zzero, af = zzero, ag = zzero, ao = zzero;
                ai = MFMA(A[0][0], b0, ai); af = MFMA(A[1][0], b0, af);
                ag = MFMA(A[2][0], b0, ag); ao = MFMA(A[3][0], b0, ao);
                ai = MFMA(A[0][1], b1, ai); af = MFMA(A[1][1], b1, af);
                ag = MFMA(A[2][1], b1, ag); ao = MFMA(A[3][1], b1, ao);
                ai = MFMA(A[0][2], b2, ai); af = MFMA(A[1][2], b2, af);
                ag = MFMA(A[2][2], b2, ag); ao = MFMA(A[3][2], b2, ao);
                half4 hv;
#pragma unroll
                for (int r = 0; r < 4; ++r) {
                    float gi = sigm(ai[r] + bv[0][r]);
                    float gf = sigm(af[r] + bv[1][r]);
                    float gg = tanh_(ag[r] + bv[2][r]);
                    float go = sigm(ao[r] + bv[3][r]);
                    c[r] = fmaf(gf, c[r], gi * gg);
                    hv[r] = (_Float16)(go * tanh_(c[r]));
                }
                // units 16*m2 + 4*q + r -> h2 slots 96 + unit
                *(half4*)(zw + el * ZROW + 96 + 16 * m2 + 4 * q) = hv;
            }
        } else if (wid == 6) {
            // ---------------- x[s+1] staging ----------------
            if (s + 1 < T_STEPS) {
#pragma unroll
                for (int i = 0; i < 4; ++i) {
                    const int idx = i * 64 + lane;
                    const int e = idx >> 5, f = idx & 31;
                    if (f < IN_DIM)
                        zw[e * ZROW + f] = (_Float16)ldv(
                            x, (long)(e0 + e) * xstr + f * T_STEPS + (s + 1), isb);
                }
            }
        }
        __syncthreads();
    }

    // ---- FC head: h2[T-1] is in z[0] slots 96..127 (written at s=1000) ----
    if (j < 128) {
        const int e = j >> 4, u = j & 15;
        float ss = ldv(b_fc1, u, isb);
#pragma unroll
        for (int k = 0; k < 32; ++k)
            ss = fmaf(ldv(w_fc1, u * 32 + k, isb),
                      (float)z[0][e * ZROW + 96 + k], ss);
        f1s[e][u] = fmaxf(ss, 0.0f);
    }
    __syncthreads();
    if (j < 80) {
        const int e = j / 10, u = j % 10;
        float ss = ldv(b_fc2, u, isb);
#pragma unroll
        for (int k = 0; k < 16; ++k)
            ss = fmaf(ldv(w_fc2, u * 16 + k, isb), f1s[e][k], ss);
        const int oidx = (e0 + e) * 10 + u;
        if (isb) ((bf16*)out)[oidx] = __float2bfloat16(ss);
        else     ((float*)out)[oidx] = ss;
    }
}

extern "C" void kernel_launch(void* const* d_in, const int* in_sizes, int n_in,
                              void* d_out, int out_size, void* d_ws, size_t ws_size,
                              hipStream_t stream) {
    lstm_mfma<<<dim3(64), dim3(512), 0, stream>>>(
        d_in[0], d_in[1], d_in[2], d_in[3], d_in[4],
        d_in[5], d_in[6], d_in[7], d_in[8],
        d_in[9], d_in[10], d_in[11], d_in[12], d_out);
}